// Round 4
// baseline (127.889 us; speedup 1.0000x reference)
//
#include <hip/hip_runtime.h>
#include <math.h>

#define NBLOBS 8
#define HID    64
#define TSZ    256
#define BATCH  256
#define EPSV   1e-6f

// exp(-0.5*(p^2+q^2)) == exp2(-(u^2+v^2)) with u,v prescaled by sqrt(0.5*log2(e))
#if __has_builtin(__builtin_amdgcn_exp2f)
#define FAST_EXP(x) __builtin_amdgcn_exp2f(x)
#define PRESCALE 0.8493218002880191f   /* sqrt(0.5*log2(e)) */
#else
#define FAST_EXP(x) __expf(x)
#define PRESCALE 0.7071067811865476f   /* sqrt(0.5) */
#endif

__device__ __forceinline__ float sigmoidf_(float x) {
    return 1.0f / (1.0f + __expf(-x));
}

// Grid (NBLOBS, 16): blockIdx.x = blob n, blockIdx.y = batch chunk of 16.
// One wave (64 threads): lane = bl + 16*q, bl = batch-in-chunk, q = k-quarter.
// Each lane computes full h1 for its b, then h2 for k in [16q,16q+16), then a
// partial bd[5]; full bd via __shfl_xor(16/32) reduction. q==0 lanes write the
// 8 quadratic-form coeffs per (n,b):
//   p0=x, p1=M=-2(AB+CD), p2=Qx=-(B^2+D^2), p3=del=-(A^2+C^2),
//   p4=-2*y*del, p5=-y, p6=del*y^2, p7=0
__global__ __launch_bounds__(64) void encode_kernel(
    const float* __restrict__ positions,  // [BATCH,6]
    const float* __restrict__ W1,         // [N,3,H]
    const float* __restrict__ b1,         // [N,H]
    const float* __restrict__ W2,         // [N,H,H]
    const float* __restrict__ b2,         // [N,H]
    const float* __restrict__ W3,         // [N,H,5]
    const float* __restrict__ b3,         // [N,5]
    const float* __restrict__ scale_ptr,  // scalar
    float* __restrict__ params)
{
    const int n   = blockIdx.x;
    const int tid = threadIdx.x;

    __shared__ float sW1[3 * HID];
    __shared__ float sB1[HID];
    __shared__ float sW2[HID * HID];
    __shared__ float sB2[HID];
    __shared__ float sW3[HID * 5];
    __shared__ float sB3[5];

    for (int i = tid; i < 3 * HID; i += 64) sW1[i] = W1[n * 3 * HID + i];
    for (int i = tid; i < HID; i += 64) {
        sB1[i] = b1[n * HID + i];
        sB2[i] = b2[n * HID + i];
    }
    {
        float4*       s4 = (float4*)sW2;
        const float4* g4 = (const float4*)(W2 + n * HID * HID);
        for (int i = tid; i < HID * HID / 4; i += 64) s4[i] = g4[i];
    }
    for (int i = tid; i < HID * 5; i += 64) sW3[i] = W3[n * HID * 5 + i];
    if (tid < 5) sB3[tid] = b3[n * 5 + tid];
    __syncthreads();

    const int bl = tid & 15;       // batch element within chunk
    const int q  = tid >> 4;       // k-quarter
    const int b  = blockIdx.y * 16 + bl;
    const int k0 = q * 16;

    // SIDE_RIGHT = [1,0,1,0,...]: even n uses positions[:, :3], odd uses [:, 3:]
    const int off = (n & 1) ? 3 : 0;
    const float p0 = positions[b * 6 + off + 0] * 100.0f;
    const float p1 = positions[b * 6 + off + 1] * 100.0f;
    const float p2 = positions[b * 6 + off + 2] * 100.0f;

    float h1[HID];
#pragma unroll
    for (int k = 0; k < HID; ++k) {
        float acc = sB1[k];
        acc = fmaf(p0, sW1[0 * HID + k], acc);
        acc = fmaf(p1, sW1[1 * HID + k], acc);
        acc = fmaf(p2, sW1[2 * HID + k], acc);
        h1[k] = fmaxf(acc, 0.0f);
    }

    // h2 quarter: k in [k0, k0+16), h-outer with float4 LDS reads.
    float acc[16];
#pragma unroll
    for (int k = 0; k < 16; ++k) acc[k] = sB2[k0 + k];
#pragma unroll
    for (int h = 0; h < HID; ++h) {
        const float xh = h1[h];
#pragma unroll
        for (int k4 = 0; k4 < 4; ++k4) {
            const float4 w = *(const float4*)&sW2[h * HID + k0 + 4 * k4];
            acc[4 * k4 + 0] = fmaf(xh, w.x, acc[4 * k4 + 0]);
            acc[4 * k4 + 1] = fmaf(xh, w.y, acc[4 * k4 + 1]);
            acc[4 * k4 + 2] = fmaf(xh, w.z, acc[4 * k4 + 2]);
            acc[4 * k4 + 3] = fmaf(xh, w.w, acc[4 * k4 + 3]);
        }
    }

    float bd[5];
#pragma unroll
    for (int j = 0; j < 5; ++j) bd[j] = (q == 0) ? sB3[j] : 0.0f;
#pragma unroll
    for (int k = 0; k < 16; ++k) {
        const float xh = fmaxf(acc[k], 0.0f);
#pragma unroll
        for (int j = 0; j < 5; ++j)
            bd[j] = fmaf(xh, sW3[(k0 + k) * 5 + j], bd[j]);
    }
    // Sum partials across the 4 k-quarters (lane ^ 16, lane ^ 32).
#pragma unroll
    for (int j = 0; j < 5; ++j) {
        bd[j] += __shfl_xor(bd[j], 16, 64);
        bd[j] += __shfl_xor(bd[j], 32, 64);
    }

    const float scale = scale_ptr[0];
    // START_Y[n] = 0.1*(n+1), START_X[n] = 0.1*(8-n), START_S = 0.05
    const float y  = sigmoidf_(bd[0]) + 0.1f * (float)(n + 1);
    const float x  = sigmoidf_(bd[1]) + 0.1f * (float)(8 - n);
    const float s  = (bd[2] + 0.05f) * scale;
    const float a  = 0.5f + sigmoidf_(bd[3]) * 1.5f;
    const float th = sigmoidf_(bd[4]) * 3.14159265358979323846f;

    float sn, c;
    sincosf(th, &sn, &c);

    const float sa = s * a + EPSV;
    const float sb = s / (a + EPSV) + EPSV;
    const float ia = PRESCALE / sa;
    const float ib = PRESCALE / sb;

    const float A = c * ia;
    const float B = sn * ia;
    const float C = -sn * ib;
    const float D = c * ib;

    const float M   = -2.0f * (A * B + C * D);
    const float Qx  = -(B * B + D * D);
    const float del = -(A * A + C * C);

    if (q == 0) {
        float4* p = (float4*)(params + (n * BATCH + b) * 8);
        p[0] = make_float4(x, M, Qx, del);
        p[1] = make_float4(-2.0f * y * del, -y, del * y * y, 0.0f);
    }
}

// Grid (TSZ/32, BATCH): blockIdx.x = 32-row group, blockIdx.y = batch b.
// 256 threads: (tid&63)*4 = starting column (owns 4 consecutive cols -> one
// float4 store per row), (tid>>6)*8 = 8-row strip within the group.
// Per blob the score is a quadratic in ci: t = (del*ci + b1c)*ci + b0c, where
// b1c/b0c depend only on cj — computed once per (blob, col), reused over 8 rows.
// Wave stores are 1 KB contiguous (global_store_dwordx4, 16 B/lane).
__global__ __launch_bounds__(256) void splat_kernel(
    const float* __restrict__ params,     // [N,BATCH,8]
    float* __restrict__ out)              // [BATCH,TSZ,TSZ]
{
    const int b = blockIdx.y;

    __shared__ float sp[NBLOBS * 8];
    if (threadIdx.x < NBLOBS * 8) {
        const int n = threadIdx.x >> 3;
        const int f = threadIdx.x & 7;
        sp[threadIdx.x] = params[(n * BATCH + b) * 8 + f];
    }
    __syncthreads();

    const int j4 = (threadIdx.x & 63) * 4;
    const int r0 = blockIdx.x * 32 + (threadIdx.x >> 6) * 8;

    float ci[8];
#pragma unroll
    for (int r = 0; r < 8; ++r)
        ci[r] = ((float)(r0 + r) + 0.5f) * (1.0f / TSZ);

    float img[4][8];
#pragma unroll
    for (int jj = 0; jj < 4; ++jj)
#pragma unroll
        for (int r = 0; r < 8; ++r) img[jj][r] = 0.0f;

#pragma unroll
    for (int n = 0; n < NBLOBS; ++n) {
        const float x    = sp[n * 8 + 0];
        const float M    = sp[n * 8 + 1];
        const float Qx   = sp[n * 8 + 2];
        const float del  = sp[n * 8 + 3];
        const float m2yd = sp[n * 8 + 4];
        const float negy = sp[n * 8 + 5];
        const float y2d  = sp[n * 8 + 6];

#pragma unroll
        for (int jj = 0; jj < 4; ++jj) {
            const float cj  = ((float)(j4 + jj) + 0.5f) * (1.0f / TSZ);
            const float dx  = cj - x;
            const float e   = M * dx;
            const float b1c = e + m2yd;
            const float b0c = fmaf(negy, e, fmaf(Qx, dx * dx, y2d));

#pragma unroll
            for (int r = 0; r < 8; ++r) {
                const float t   = fmaf(ci[r], fmaf(ci[r], del, b1c), b0c);
                const float cur = FAST_EXP(t);
                img[jj][r] = fmaf(img[jj][r], cur, cur);
            }
        }
    }

    float* base = out + (size_t)b * TSZ * TSZ + (size_t)r0 * TSZ + j4;
#pragma unroll
    for (int r = 0; r < 8; ++r) {
        float4 v = make_float4(img[0][r], img[1][r], img[2][r], img[3][r]);
        *(float4*)(base + (size_t)r * TSZ) = v;
    }
}

extern "C" void kernel_launch(void* const* d_in, const int* in_sizes, int n_in,
                              void* d_out, int out_size, void* d_ws, size_t ws_size,
                              hipStream_t stream) {
    const float* positions = (const float*)d_in[0];
    const float* W1        = (const float*)d_in[1];
    const float* b1        = (const float*)d_in[2];
    const float* W2        = (const float*)d_in[3];
    const float* b2        = (const float*)d_in[4];
    const float* W3        = (const float*)d_in[5];
    const float* b3        = (const float*)d_in[6];
    // d_in[7] = target_size (fixed 256); d_in[8] = blobs_scale_factor
    const float* scale_ptr = (const float*)d_in[8];

    float* params = (float*)d_ws;  // NBLOBS*BATCH*8 floats = 64 KB
    float* out    = (float*)d_out;

    encode_kernel<<<dim3(NBLOBS, BATCH / 16), dim3(64), 0, stream>>>(
        positions, W1, b1, W2, b2, W3, b3, scale_ptr, params);

    splat_kernel<<<dim3(TSZ / 32, BATCH), dim3(256), 0, stream>>>(params, out);
}

// Round 5
// 117.097 us; speedup vs baseline: 1.0922x; 1.0922x over previous
//
#include <hip/hip_runtime.h>
#include <math.h>

#define NBLOBS 8
#define HID    64
#define TSZ    256
#define BATCH  256
#define EPSV   1e-6f

// exp(-0.5*(p^2+q^2)) == exp2(-(u^2+v^2)) with u,v prescaled by sqrt(0.5*log2(e))
#if __has_builtin(__builtin_amdgcn_exp2f)
#define FAST_EXP(x) __builtin_amdgcn_exp2f(x)
#define PRESCALE 0.8493218002880191f   /* sqrt(0.5*log2(e)) */
#else
#define FAST_EXP(x) __expf(x)
#define PRESCALE 0.7071067811865476f   /* sqrt(0.5) */
#endif

__device__ __forceinline__ float sigmoidf_(float x) {
    return 1.0f / (1.0f + __expf(-x));
}

// Grid (NBLOBS, 16): blockIdx.x = blob n, blockIdx.y = batch chunk of 16.
// One wave (64 threads): lane = bl + 16*q, bl = batch-in-chunk, q = k-quarter.
// Each lane computes full h1 for its b, then h2 for k in [16q,16q+16), then a
// partial bd[5]; full bd via __shfl_xor(16/32) reduction. q==0 lanes write the
// 8 quadratic-form coeffs per (n,b):
//   p0=x, p1=M=-2(AB+CD), p2=Qx=-(B^2+D^2), p3=del=-(A^2+C^2),
//   p4=-2*y*del, p5=-y, p6=del*y^2, p7=0
__global__ __launch_bounds__(64) void encode_kernel(
    const float* __restrict__ positions,  // [BATCH,6]
    const float* __restrict__ W1,         // [N,3,H]
    const float* __restrict__ b1,         // [N,H]
    const float* __restrict__ W2,         // [N,H,H]
    const float* __restrict__ b2,         // [N,H]
    const float* __restrict__ W3,         // [N,H,5]
    const float* __restrict__ b3,         // [N,5]
    const float* __restrict__ scale_ptr,  // scalar
    float* __restrict__ params)
{
    const int n   = blockIdx.x;
    const int tid = threadIdx.x;

    __shared__ float sW1[3 * HID];
    __shared__ float sB1[HID];
    __shared__ float sW2[HID * HID];
    __shared__ float sB2[HID];
    __shared__ float sW3[HID * 5];
    __shared__ float sB3[5];

    for (int i = tid; i < 3 * HID; i += 64) sW1[i] = W1[n * 3 * HID + i];
    for (int i = tid; i < HID; i += 64) {
        sB1[i] = b1[n * HID + i];
        sB2[i] = b2[n * HID + i];
    }
    {
        float4*       s4 = (float4*)sW2;
        const float4* g4 = (const float4*)(W2 + n * HID * HID);
        for (int i = tid; i < HID * HID / 4; i += 64) s4[i] = g4[i];
    }
    for (int i = tid; i < HID * 5; i += 64) sW3[i] = W3[n * HID * 5 + i];
    if (tid < 5) sB3[tid] = b3[n * 5 + tid];
    __syncthreads();

    const int bl = tid & 15;       // batch element within chunk
    const int q  = tid >> 4;       // k-quarter
    const int b  = blockIdx.y * 16 + bl;
    const int k0 = q * 16;

    // SIDE_RIGHT = [1,0,1,0,...]: even n uses positions[:, :3], odd uses [:, 3:]
    const int off = (n & 1) ? 3 : 0;
    const float p0 = positions[b * 6 + off + 0] * 100.0f;
    const float p1 = positions[b * 6 + off + 1] * 100.0f;
    const float p2 = positions[b * 6 + off + 2] * 100.0f;

    float h1[HID];
#pragma unroll
    for (int k = 0; k < HID; ++k) {
        float acc = sB1[k];
        acc = fmaf(p0, sW1[0 * HID + k], acc);
        acc = fmaf(p1, sW1[1 * HID + k], acc);
        acc = fmaf(p2, sW1[2 * HID + k], acc);
        h1[k] = fmaxf(acc, 0.0f);
    }

    // h2 quarter: k in [k0, k0+16), h-outer with float4 LDS reads.
    float acc[16];
#pragma unroll
    for (int k = 0; k < 16; ++k) acc[k] = sB2[k0 + k];
#pragma unroll
    for (int h = 0; h < HID; ++h) {
        const float xh = h1[h];
#pragma unroll
        for (int k4 = 0; k4 < 4; ++k4) {
            const float4 w = *(const float4*)&sW2[h * HID + k0 + 4 * k4];
            acc[4 * k4 + 0] = fmaf(xh, w.x, acc[4 * k4 + 0]);
            acc[4 * k4 + 1] = fmaf(xh, w.y, acc[4 * k4 + 1]);
            acc[4 * k4 + 2] = fmaf(xh, w.z, acc[4 * k4 + 2]);
            acc[4 * k4 + 3] = fmaf(xh, w.w, acc[4 * k4 + 3]);
        }
    }

    float bd[5];
#pragma unroll
    for (int j = 0; j < 5; ++j) bd[j] = (q == 0) ? sB3[j] : 0.0f;
#pragma unroll
    for (int k = 0; k < 16; ++k) {
        const float xh = fmaxf(acc[k], 0.0f);
#pragma unroll
        for (int j = 0; j < 5; ++j)
            bd[j] = fmaf(xh, sW3[(k0 + k) * 5 + j], bd[j]);
    }
    // Sum partials across the 4 k-quarters (lane ^ 16, lane ^ 32).
#pragma unroll
    for (int j = 0; j < 5; ++j) {
        bd[j] += __shfl_xor(bd[j], 16, 64);
        bd[j] += __shfl_xor(bd[j], 32, 64);
    }

    const float scale = scale_ptr[0];
    // START_Y[n] = 0.1*(n+1), START_X[n] = 0.1*(8-n), START_S = 0.05
    const float y  = sigmoidf_(bd[0]) + 0.1f * (float)(n + 1);
    const float x  = sigmoidf_(bd[1]) + 0.1f * (float)(8 - n);
    const float s  = (bd[2] + 0.05f) * scale;
    const float a  = 0.5f + sigmoidf_(bd[3]) * 1.5f;
    const float th = sigmoidf_(bd[4]) * 3.14159265358979323846f;

    float sn, c;
    sincosf(th, &sn, &c);

    const float sa = s * a + EPSV;
    const float sb = s / (a + EPSV) + EPSV;
    const float ia = PRESCALE / sa;
    const float ib = PRESCALE / sb;

    const float A = c * ia;
    const float B = sn * ia;
    const float C = -sn * ib;
    const float D = c * ib;

    const float M   = -2.0f * (A * B + C * D);
    const float Qx  = -(B * B + D * D);
    const float del = -(A * A + C * C);

    if (q == 0) {
        float4* p = (float4*)(params + (n * BATCH + b) * 8);
        p[0] = make_float4(x, M, Qx, del);
        p[1] = make_float4(-2.0f * y * del, -y, del * y * y, 0.0f);
    }
}

// Grid (4, 8, BATCH): blockIdx.x = 64-col group, blockIdx.y = 32-row group,
// blockIdx.z = batch. 256 threads: (tid&63) = column, (tid>>6) = 8-row strip.
// Each thread owns an 8-row column strip; per blob the score is a quadratic
// in ci: t = (del*ci + b1c)*ci + b0c (b1c,b0c depend only on this thread's cj).
// Stores: 64 consecutive lanes x 4 B = 256 B/inst contiguous (fully coalesced);
// low VGPR (~40) keeps 8 waves/SIMD — the 4-col float4 variant halved occupancy
// and regressed +10 us (R4), so scalar-store/8-row layout is the keeper.
__global__ __launch_bounds__(256) void splat_kernel(
    const float* __restrict__ params,     // [N,BATCH,8]
    float* __restrict__ out)              // [BATCH,TSZ,TSZ]
{
    const int b = blockIdx.z;

    __shared__ float sp[NBLOBS * 8];
    if (threadIdx.x < NBLOBS * 8) {
        const int n = threadIdx.x >> 3;
        const int f = threadIdx.x & 7;
        sp[threadIdx.x] = params[(n * BATCH + b) * 8 + f];
    }
    __syncthreads();

    const int j  = blockIdx.x * 64 + (threadIdx.x & 63);
    const int r0 = blockIdx.y * 32 + (threadIdx.x >> 6) * 8;
    const float cj = ((float)j + 0.5f) * (1.0f / TSZ);

    float ci[8];
#pragma unroll
    for (int r = 0; r < 8; ++r)
        ci[r] = ((float)(r0 + r) + 0.5f) * (1.0f / TSZ);

    float img[8];
#pragma unroll
    for (int r = 0; r < 8; ++r) img[r] = 0.0f;

#pragma unroll
    for (int n = 0; n < NBLOBS; ++n) {
        const float x    = sp[n * 8 + 0];
        const float M    = sp[n * 8 + 1];
        const float Qx   = sp[n * 8 + 2];
        const float del  = sp[n * 8 + 3];
        const float m2yd = sp[n * 8 + 4];
        const float negy = sp[n * 8 + 5];
        const float y2d  = sp[n * 8 + 6];

        const float dx  = cj - x;
        const float e   = M * dx;
        const float b1c = e + m2yd;
        const float b0c = fmaf(negy, e, fmaf(Qx, dx * dx, y2d));

#pragma unroll
        for (int r = 0; r < 8; ++r) {
            const float t   = fmaf(ci[r], fmaf(ci[r], del, b1c), b0c);
            const float cur = FAST_EXP(t);
            img[r] = fmaf(img[r], cur, cur);
        }
    }

    float* dst = out + (size_t)b * TSZ * TSZ + (size_t)r0 * TSZ + j;
#pragma unroll
    for (int r = 0; r < 8; ++r) dst[r * TSZ] = img[r];
}

extern "C" void kernel_launch(void* const* d_in, const int* in_sizes, int n_in,
                              void* d_out, int out_size, void* d_ws, size_t ws_size,
                              hipStream_t stream) {
    const float* positions = (const float*)d_in[0];
    const float* W1        = (const float*)d_in[1];
    const float* b1        = (const float*)d_in[2];
    const float* W2        = (const float*)d_in[3];
    const float* b2        = (const float*)d_in[4];
    const float* W3        = (const float*)d_in[5];
    const float* b3        = (const float*)d_in[6];
    // d_in[7] = target_size (fixed 256); d_in[8] = blobs_scale_factor
    const float* scale_ptr = (const float*)d_in[8];

    float* params = (float*)d_ws;  // NBLOBS*BATCH*8 floats = 64 KB
    float* out    = (float*)d_out;

    encode_kernel<<<dim3(NBLOBS, BATCH / 16), dim3(64), 0, stream>>>(
        positions, W1, b1, W2, b2, W3, b3, scale_ptr, params);

    splat_kernel<<<dim3(TSZ / 64, TSZ / 32, BATCH), dim3(256), 0, stream>>>(params, out);
}